// Round 12
// baseline (115.368 us; speedup 1.0000x reference)
//
#include <hip/hip_runtime.h>

typedef __attribute__((ext_vector_type(8))) _Float16 f16x8;
typedef __attribute__((ext_vector_type(4))) _Float16 f16x4;
typedef __attribute__((ext_vector_type(4))) float    f32x4;

constexpr int Bsz = 32768;
constexpr int Hn  = 256;
constexpr int In  = 128;
constexpr long long BH = (long long)Bsz * Hn;

// ---------------------------------------------------------------------------
// prep: weights -> fp16, PRE-SWIZZLED into MFMA-fragment-linear order.
// Tile (cg, t): lane l holds W[cg*16 + (l&15)][t*32 + (l>>4)*8 ..+8],
// stored at ((cg*NT + t)*64 + l)*8 halves.
// ws half-layout: Gh [0,64K) | Gm [64K,128K) | Wr [128K,192K) | Wi [192K,224K)
// ---------------------------------------------------------------------------
__global__ __launch_bounds__(256) void k_prep(
    const float* __restrict__ Wi, const float* __restrict__ Wr,
    const float* __restrict__ Gc, _Float16* __restrict__ ws)
{
    const int idx = blockIdx.x * 256 + threadIdx.x;   // 0..65535
    {   // Gh/Gm/Wr: K=256, NT=8
        const int cg = idx >> 12, rem = idx & 4095;
        const int t = rem >> 9, l = (rem >> 3) & 63, j = idx & 7;
        const int col = cg * 16 + (l & 15);
        const int k   = t * 32 + (l >> 4) * 8 + j;
        float g = Gc[col * Hn + k];
        _Float16 gh = (_Float16)g;
        ws[idx]         = gh;
        ws[65536 + idx] = (_Float16)((g - (float)gh) * 4096.0f);
        ws[131072 + idx] = (_Float16)Wr[col * Hn + k];
    }
    if (idx < 32768) {  // Wi: K=128, NT=4
        const int cg = idx >> 11, rem = idx & 2047;
        const int t = rem >> 9, l = (rem >> 3) & 63, j = idx & 7;
        const int col = cg * 16 + (l & 15);
        const int k   = t * 32 + (l >> 4) * 8 + j;
        ws[196608 + idx] = (_Float16)Wi[col * In + k];
    }
}

// LDS swizzled byte offsets
__device__ __forceinline__ int swzH(int row, int colh) {   // fp16 [32][256]
    return (row * 512 + colh * 2) ^ ((row & 7) << 4);
}
__device__ __forceinline__ int swzX(int row, int colh) {   // fp16 [32][128]
    return (row * 256 + colh * 2) ^ ((row & 7) << 4);
}

__device__ __forceinline__ f16x4 cvt4h(float4 a) {
    f16x4 r;
    r[0] = (_Float16)a.x; r[1] = (_Float16)a.y;
    r[2] = (_Float16)a.z; r[3] = (_Float16)a.w;
    return r;
}
__device__ __forceinline__ f16x4 cvt4m(float4 a) {
    float f[4] = {a.x, a.y, a.z, a.w};
    f16x4 r;
    #pragma unroll
    for (int k = 0; k < 4; ++k) {
        _Float16 h = (_Float16)f[k];
        r[k] = (_Float16)((f[k] - (float)h) * 4096.0f);
    }
    return r;
}

#define MFMA16(A, B, C) __builtin_amdgcn_mfma_f32_16x16x32_f16(A, B, C, 0, 0, 0)

// staged-stripe registers (static names; no dynamic indexing)
struct SRegs { float4 va[4], za[4], xa[2]; };

__device__ __forceinline__ void ld_regs(
    int rowBase, int tid,
    const float* __restrict__ v, const float* __restrict__ z,
    const float* __restrict__ x, SRegs& R)
{
    const float4* vsrc = (const float4*)(v + (size_t)rowBase * Hn);
    const float4* zsrc = (const float4*)(z + (size_t)rowBase * Hn);
    const float4* xsrc = (const float4*)(x + (size_t)rowBase * In);
    #pragma unroll
    for (int k = 0; k < 4; ++k) R.va[k] = vsrc[k * 512 + tid];
    #pragma unroll
    for (int k = 0; k < 4; ++k) R.za[k] = zsrc[k * 512 + tid];
    #pragma unroll
    for (int k = 0; k < 2; ++k) R.xa[k] = xsrc[k * 512 + tid];
}

__device__ __forceinline__ void write_stage(
    int tid, char* VH, char* VM, char* ZH, char* XH, const SRegs& R)
{
    #pragma unroll
    for (int k = 0; k < 4; ++k) {
        const int f = k * 512 + tid;
        const int row = f >> 6, c4 = (f & 63) * 4;
        *(f16x4*)(VH + swzH(row, c4)) = cvt4h(R.va[k]);
        *(f16x4*)(VM + swzH(row, c4)) = cvt4m(R.va[k]);
        *(f16x4*)(ZH + swzH(row, c4)) = cvt4h(R.za[k]);
    }
    #pragma unroll
    for (int k = 0; k < 2; ++k) {
        const int f = k * 512 + tid;
        const int row = f >> 5, c4 = (f & 31) * 4;
        *(f16x4*)(XH + swzX(row, c4)) = cvt4h(R.xa[k]);
    }
}

// ---------------------------------------------------------------------------
// main: 512 blocks x 512 thr; each block does 2 stripes of BT=32 rows,
// software-pipelined: stripe s+1 global loads in flight during k-loop s.
// LDS 57344 B: VH 16K | VM 16K | ZH 16K | XH 8K (single buffer, reused).
// Epilogue: direct scatter from fragment layout (64-B sector-aligned),
// no LDS transpose, no aux buffer. 3 barriers per block total.
// Math identical to R11 (bit-identical outputs).
// ---------------------------------------------------------------------------
__global__ __launch_bounds__(512, 4) void k_main(
    const float* __restrict__ x, const float* __restrict__ z,
    const float* __restrict__ v, const float* __restrict__ cur,
    const float* __restrict__ rho, const _Float16* __restrict__ ws,
    float* __restrict__ out)
{
    __shared__ char smem[57344];
    char* VH = smem;             // 16 KB fp16 [32][256]
    char* VM = smem + 16384;     // 16 KB
    char* ZH = smem + 32768;     // 16 KB
    char* XH = smem + 49152;     // 8 KB fp16 [32][128]

    const int tid  = threadIdx.x;         // 0..511
    const int lane = tid & 63;
    const int ln = lane & 15, lg = lane >> 4;
    const int w  = tid >> 6;              // wave 0..7
    const int sb0 = blockIdx.x * 64;      // stripe 0 rows
    const int sb1 = sb0 + 32;             // stripe 1 rows

    const _Float16* Gh  = ws;
    const _Float16* Gm  = ws + 65536;
    const _Float16* Wr  = ws + 131072;
    const _Float16* Wi  = ws + 196608;

    float* out_z   = out;
    float* out_v   = out + BH;
    float* out_i   = out + 2 * BH;
    float* out_rho = out + 3 * BH;

    // ---- k-loop over the staged stripe (identical math to R11) ----
    auto kloop = [&](f32x4 (&acc_c)[2][2], f32x4 (&acc_cm)[2][2],
                     f32x4 (&acc_i)[2][2]) {
        #pragma unroll
        for (int m = 0; m < 2; ++m)
            #pragma unroll
            for (int c = 0; c < 2; ++c) {
                acc_c[m][c]  = (f32x4){0.f, 0.f, 0.f, 0.f};
                acc_cm[m][c] = (f32x4){0.f, 0.f, 0.f, 0.f};
                acc_i[m][c]  = (f32x4){0.f, 0.f, 0.f, 0.f};
            }
        #pragma unroll 2
        for (int t = 0; t < 8; ++t) {
            const int kf = t * 32 + lg * 8;
            f16x8 vh0 = *(const f16x8*)(VH + swzH(ln,      kf));
            f16x8 vh1 = *(const f16x8*)(VH + swzH(ln + 16, kf));
            f16x8 vm0 = *(const f16x8*)(VM + swzH(ln,      kf));
            f16x8 vm1 = *(const f16x8*)(VM + swzH(ln + 16, kf));
            f16x8 zh0 = *(const f16x8*)(ZH + swzH(ln,      kf));
            f16x8 zh1 = *(const f16x8*)(ZH + swzH(ln + 16, kf));
            f16x8 xh0, xh1;
            if (t < 4) {
                xh0 = *(const f16x8*)(XH + swzX(ln,      kf));
                xh1 = *(const f16x8*)(XH + swzX(ln + 16, kf));
            }
            #pragma unroll
            for (int c = 0; c < 2; ++c) {
                const int cg = w * 2 + c;
                f16x8 bgh = *(const f16x8*)(Gh + ((size_t)(cg * 8 + t) * 64 + lane) * 8);
                f16x8 bgm = *(const f16x8*)(Gm + ((size_t)(cg * 8 + t) * 64 + lane) * 8);
                f16x8 bwr = *(const f16x8*)(Wr + ((size_t)(cg * 8 + t) * 64 + lane) * 8);
                acc_c[0][c]  = MFMA16(vh0, bgh, acc_c[0][c]);
                acc_c[1][c]  = MFMA16(vh1, bgh, acc_c[1][c]);
                acc_cm[0][c] = MFMA16(vh0, bgm, acc_cm[0][c]);
                acc_cm[1][c] = MFMA16(vh1, bgm, acc_cm[1][c]);
                acc_cm[0][c] = MFMA16(vm0, bgh, acc_cm[0][c]);
                acc_cm[1][c] = MFMA16(vm1, bgh, acc_cm[1][c]);
                acc_i[0][c]  = MFMA16(zh0, bwr, acc_i[0][c]);
                acc_i[1][c]  = MFMA16(zh1, bwr, acc_i[1][c]);
                if (t < 4) {
                    f16x8 bwi = *(const f16x8*)(Wi + ((size_t)(cg * 4 + t) * 64 + lane) * 8);
                    acc_i[0][c] = MFMA16(xh0, bwi, acc_i[0][c]);
                    acc_i[1][c] = MFMA16(xh1, bwi, acc_i[1][c]);
                }
            }
        }
        // fold split-fp16 correction
        #pragma unroll
        for (int m = 0; m < 2; ++m)
            #pragma unroll
            for (int c = 0; c < 2; ++c)
                acc_c[m][c] = acc_c[m][c] + acc_cm[m][c] * 2.44140625e-4f;
    };

    // ---- epilogue: direct scatter from fragment layout (sector-aligned) ----
    auto epilogue = [&](int sb, f32x4 (&acc_c)[2][2], f32x4 (&acc_i)[2][2]) {
        #pragma unroll
        for (int m = 0; m < 2; ++m)
            #pragma unroll
            for (int c = 0; c < 2; ++c) {
                const int col = (w * 2 + c) * 16 + ln;
                const int rowb = sb + m * 16 + lg * 4;
                #pragma unroll
                for (int r = 0; r < 4; ++r) {
                    const size_t idx = (size_t)(rowb + r) * Hn + col;
                    const float vv = v[idx];
                    const float ii = cur[idx];
                    const float rh = rho[idx];
                    float dv   = 0.1f * ((0.0f - vv) + ii) + acc_c[m][c][r];
                    float vdec = vv + dv;
                    float zf   = (vdec - 1.0f) > 0.0f ? 1.0f : 0.0f;
                    float vnew = (1.0f - zf) * vdec;              // V_RESET = 0
                    float mask = rh > 0.0f ? 1.0f : 0.0f;
                    vnew = (1.0f - mask) * vnew + mask * vv;
                    zf   = (1.0f - mask) * zf;
                    float rhon = (1.0f - zf) * fmaxf(rh - mask, 0.0f) + zf * 5.0f;
                    out_z[idx]   = zf;
                    out_v[idx]   = vnew;
                    out_rho[idx] = rhon;
                    out_i[idx]   = 0.8f * ii + acc_i[m][c][r];
                }
            }
    };

    // ================= pipeline =================
    SRegs R0, R1;
    ld_regs(sb0, tid, v, z, x, R0);
    write_stage(tid, VH, VM, ZH, XH, R0);
    __syncthreads();                                   // B1

    // stripe 0: prefetch stripe 1 while computing
    ld_regs(sb1, tid, v, z, x, R1);
    f32x4 acc_c[2][2], acc_cm[2][2], acc_i[2][2];
    kloop(acc_c, acc_cm, acc_i);
    __syncthreads();                                   // B2: stage reads done
    write_stage(tid, VH, VM, ZH, XH, R1);
    epilogue(sb0, acc_c, acc_i);                       // global IO only
    __syncthreads();                                   // B3: stage 1 ready

    // stripe 1
    kloop(acc_c, acc_cm, acc_i);
    epilogue(sb1, acc_c, acc_i);
}

extern "C" void kernel_launch(void* const* d_in, const int* in_sizes, int n_in,
                              void* d_out, int out_size, void* d_ws, size_t ws_size,
                              hipStream_t stream) {
    const float* x   = (const float*)d_in[0];
    const float* z   = (const float*)d_in[1];
    const float* v   = (const float*)d_in[2];
    const float* cur = (const float*)d_in[3];
    const float* rho = (const float*)d_in[4];
    const float* Wi  = (const float*)d_in[5];
    const float* Wr  = (const float*)d_in[6];
    const float* Gc  = (const float*)d_in[7];
    float* out = (float*)d_out;
    _Float16* ws = (_Float16*)d_ws;   // needs 458752 B

    hipLaunchKernelGGL(k_prep, dim3(256), dim3(256), 0, stream, Wi, Wr, Gc, ws);
    hipLaunchKernelGGL(k_main, dim3(512), dim3(512), 0, stream,
                       x, z, v, cur, rho, ws, out);
}